// Round 18
// baseline (62.487 us; speedup 1.0000x reference)
//
#include <hip/hip_runtime.h>
#include <hip/hip_bf16.h>

#define N 2048
#define FEAT 2048
#define K_NEG 10
#define NCLS 288
#define M1 0.3f
#define M2 0.3f
#define CW 0.01f

#define BT 64                 // square tile (symmetric/triangular grid)
#define GT (N / BT)           // 32 tiles per side
#define NBLK (GT * (GT + 1) / 2)   // 528 triangular blocks
#define BK 64
#define NT (FEAT / BK)        // 32 K-steps
#define NRB (N * K_NEG / 256) // 80 reduce blocks

typedef __attribute__((ext_vector_type(8))) __bf16 bf16x8;
typedef __attribute__((ext_vector_type(4))) float f32x4;
typedef unsigned long long u64;

__device__ __forceinline__ unsigned short f32_to_bf16(float f) {
    unsigned int u = __float_as_uint(f);
    u += 0x7fffu + ((u >> 16) & 1u);   // round-to-nearest-even
    return (unsigned short)(u >> 16);
}

__device__ __forceinline__ unsigned int rotl32(unsigned int x, int d) {
    return (x << d) | (x >> (32 - d));
}

// Exact replica of jax.random.uniform(jax.random.key(42), (2048,2048)) at flat index f.
__device__ __attribute__((noinline)) float threefry_uniform(unsigned int f) {
    const unsigned int H = (unsigned int)(N) * (unsigned int)(N) / 2u;
    unsigned int x0, x1; int word;
    if (f < H) { x0 = f;     x1 = f + H; word = 0; }
    else       { x0 = f - H; x1 = f;     word = 1; }
    unsigned int ks[3];
    ks[0] = 0u; ks[1] = 42u; ks[2] = 0u ^ 42u ^ 0x1BD11BDAu;
    x0 += ks[0]; x1 += ks[1];
    const int rotA[4] = {13, 15, 26, 6};
    const int rotB[4] = {17, 29, 16, 24};
    #pragma unroll
    for (int i = 0; i < 5; ++i) {
        const int* r = (i & 1) ? rotB : rotA;
        #pragma unroll
        for (int j = 0; j < 4; ++j) {
            x0 += x1; x1 = rotl32(x1, r[j]); x1 ^= x0;
        }
        x0 += ks[(i + 1) % 3];
        x1 += ks[(i + 2) % 3] + (unsigned int)(i + 1);
    }
    unsigned int bits = (word == 0) ? x0 : x1;
    return __uint_as_float((bits >> 9) | 0x3f800000u) - 1.0f;
}

// async 16B global -> LDS (linear dest = wave-uniform base + lane*16)
__device__ __forceinline__ void gld16(const unsigned short* g, unsigned short* l) {
    __builtin_amdgcn_global_load_lds(
        (const __attribute__((address_space(1))) unsigned int*)g,
        (__attribute__((address_space(3))) unsigned int*)l,
        16, 0, 0);
}

__device__ __forceinline__ u64 shfl_xor_u64(u64 v, int mask) {
    unsigned int lo = (unsigned int)v, hi = (unsigned int)(v >> 32);
    lo = __shfl_xor(lo, mask);
    hi = __shfl_xor(hi, mask);
    return ((u64)hi << 32) | (u64)lo;
}

// Kernel A: prep, ONE WAVE PER ROW (512 blocks x 4 waves, no LDS, no barriers). (frozen)
__global__ void __launch_bounds__(256) prep_kernel(
        const float* __restrict__ emb, const int* __restrict__ labels,
        const float* __restrict__ centers, unsigned short* __restrict__ xbf,
        float* __restrict__ sq, float* __restrict__ centerp) {
    int t = threadIdx.x;
    int lane = t & 63, w = t >> 6;
    int i = blockIdx.x * 4 + w;
    int lab = labels[i];
    const float4* erow = (const float4*)(emb + (size_t)i * FEAT);
    const float4* crow = (const float4*)(centers + (size_t)lab * FEAT);
    uint2* xrow = (uint2*)(xbf + (size_t)i * FEAT);
    float ssum = 0.f, csum = 0.f;
    #pragma unroll
    for (int q = 0; q < 8; ++q) {
        int idx4 = q * 64 + lane;
        float4 e = erow[idx4];
        float4 c = crow[idx4];
        ssum += e.x*e.x + e.y*e.y + e.z*e.z + e.w*e.w;
        float dx = e.x-c.x, dy = e.y-c.y, dz = e.z-c.z, dw = e.w-c.w;
        csum += dx*dx + dy*dy + dz*dz + dw*dw;
        unsigned int w0 = (unsigned int)f32_to_bf16(e.x) | ((unsigned int)f32_to_bf16(e.y) << 16);
        unsigned int w1 = (unsigned int)f32_to_bf16(e.z) | ((unsigned int)f32_to_bf16(e.w) << 16);
        xrow[idx4] = make_uint2(w0, w1);
    }
    #pragma unroll
    for (int off = 32; off; off >>= 1) {
        ssum += __shfl_xor(ssum, off);
        csum += __shfl_xor(csum, off);
    }
    if (lane == 0) { sq[i] = ssum; centerp[i] = csum; }
}

// Kernel B: symmetric G = X X^T, triangular grid, depth-2 counted-vmcnt pipeline.
// NEW: super-tile-major tile enumeration chunked by blockIdx residue (= XCD):
// each XCD's 66 co-resident tiles span ~10-11 panels (~2.7 MB) -> fits 4 MB L2,
// converting the 11 TB/s L3-bound staging into XCD-local L2 hits.
__global__ void __launch_bounds__(256) gemm_dist_kernel(
        const unsigned short* __restrict__ xbf, const float* __restrict__ sq,
        float* __restrict__ dist) {
    __shared__ __align__(16) unsigned short smem[6 * BT * BK];   // 48 KB: 3 x (As+Bs)
    unsigned short (*As)[BT * BK] = (unsigned short(*)[BT * BK])smem;
    unsigned short (*Bs)[BT * BK] = (unsigned short(*)[BT * BK])(smem + 3 * BT * BK);
    float (*Ts)[68] = (float(*)[68])smem;   // 17408 B, aliased post-K-loop

    // bid -> tile via super-tile-major (4x4) order, chunked per residue class.
    // ord = (bid%8)*66 + bid/8 walks the ST-major permutation (bijective: 528).
    int bid = blockIdx.x;
    int ord = (bid & 7) * (NBLK / 8) + (bid >> 3);
    int by = 0, bx = 0;
    {
        bool found = false;
        for (int sy = 0; sy < 8 && !found; ++sy) {
            for (int sx = sy; sx < 8 && !found; ++sx) {
                int nt = (sx == sy) ? 10 : 16;
                if (ord < nt) {
                    int ty, tx;
                    if (sx == sy) {
                        int o = ord; ty = 0;
                        while (o >= 4 - ty) { o -= 4 - ty; ++ty; }
                        tx = ty + o;
                    } else {
                        ty = ord >> 2; tx = ord & 3;
                    }
                    by = sy * 4 + ty; bx = sx * 4 + tx;
                    found = true;
                } else {
                    ord -= nt;
                }
            }
        }
    }
    int brow0 = by * BT;
    int bcol0 = bx * BT;

    int t = threadIdx.x;
    int lane = t & 63, wid = t >> 6;
    int wr = wid >> 1, wc = wid & 1;          // 2 x 2 wave grid, 32x32 per wave
    f32x4 acc[2][2] = {};

    #define STAGE(buf, kelem) do {                                              \
        _Pragma("unroll")                                                       \
        for (int q = 0; q < 2; ++q) {                                           \
            int chunk = q * 256 + t;                                            \
            int row = chunk >> 3, c16 = chunk & 7;                              \
            int csrc = c16 ^ (row & 7);   /* involutive pre-swizzle */          \
            gld16(xbf + (size_t)(brow0 + row) * FEAT + (kelem) + csrc * 8,      \
                  &As[buf][chunk * 8]);                                         \
            gld16(xbf + (size_t)(bcol0 + row) * FEAT + (kelem) + csrc * 8,      \
                  &Bs[buf][chunk * 8]);                                         \
        } } while (0)

    STAGE(0, 0);
    STAGE(1, BK);

    for (int kt = 0; kt < NT; ++kt) {
        int cur = kt % 3;
        if (kt + 2 < NT) {
            STAGE((kt + 2) % 3, (kt + 2) * BK);                  // 12 in flight
            asm volatile("s_waitcnt vmcnt(8)" ::: "memory");     // tile-kt landed
        } else if (kt + 2 == NT) {
            asm volatile("s_waitcnt vmcnt(4)" ::: "memory");
        } else {
            asm volatile("s_waitcnt vmcnt(0)" ::: "memory");
        }
        __builtin_amdgcn_s_barrier();
        asm volatile("" ::: "memory");

        bf16x8 a[2][2], b[2][2];
        #pragma unroll
        for (int kk = 0; kk < 2; ++kk) {
            #pragma unroll
            for (int m = 0; m < 2; ++m) {
                int r = wr * 32 + m * 16 + (lane & 15);
                int slot = (kk * 4 + (lane >> 4)) ^ (r & 7);
                a[kk][m] = *(const bf16x8*)(&As[cur][r * BK + slot * 8]);
            }
            #pragma unroll
            for (int n = 0; n < 2; ++n) {
                int r = wc * 32 + n * 16 + (lane & 15);
                int slot = (kk * 4 + (lane >> 4)) ^ (r & 7);
                b[kk][n] = *(const bf16x8*)(&Bs[cur][r * BK + slot * 8]);
            }
        }
        #pragma unroll
        for (int m = 0; m < 2; ++m)
            #pragma unroll
            for (int n = 0; n < 2; ++n)
                #pragma unroll
                for (int kk = 0; kk < 2; ++kk)
                    acc[m][n] = __builtin_amdgcn_mfma_f32_16x16x32_bf16(a[kk][m], b[kk][n], acc[m][n], 0, 0, 0);

        asm volatile("" ::: "memory");
        __builtin_amdgcn_s_barrier();
        asm volatile("" ::: "memory");
    }
    #undef STAGE

    // Epilogue. C/D layout: col = lane&15, row = (lane>>4)*4 + reg  [m89/m91]
    bool offdiag = (bx != by);
    #pragma unroll
    for (int m = 0; m < 2; ++m) {
        int lrow_base = wr * 32 + m * 16 + (lane >> 4) * 4;
        #pragma unroll
        for (int n = 0; n < 2; ++n) {
            int lcol = wc * 32 + n * 16 + (lane & 15);
            int gcol = bcol0 + lcol;
            float sqc = sq[gcol];
            #pragma unroll
            for (int r = 0; r < 4; ++r) {
                int lrow = lrow_base + r;
                int grow = brow0 + lrow;
                float d2 = sq[grow] + sqc - 2.0f * acc[m][n][r];
                float d = sqrtf(fmaxf(d2, 1e-12f));
                dist[(size_t)grow * N + gcol] = d;
                if (offdiag) Ts[lcol][lrow] = d;
            }
        }
    }
    asm volatile("s_waitcnt lgkmcnt(0)" ::: "memory");
    __builtin_amdgcn_s_barrier();
    asm volatile("" ::: "memory");
    if (offdiag) {
        int tr = t >> 2, seg = t & 3;
        float4* dst = (float4*)(dist + (size_t)(bcol0 + tr) * N + brow0 + seg * 16);
        const float* srow = &Ts[tr][seg * 16];
        #pragma unroll
        for (int x = 0; x < 4; ++x)
            dst[x] = *(const float4*)(srow + x * 4);
    }
}

// Kernel C: ONE WAVE PER ROW topk (frozen) + zeroes the reduce accumulators.
__global__ void __launch_bounds__(256) topk_kernel(
        const float* __restrict__ dist, const int* __restrict__ labels,
        float* __restrict__ d_ap, int* __restrict__ avalid,
        int* __restrict__ negs1, float* __restrict__ d_an,
        float* __restrict__ rmin1, int* __restrict__ rc1, float* __restrict__ rmin2,
        unsigned long long* __restrict__ accum_ts,
        unsigned int* __restrict__ accum_vs, unsigned int* __restrict__ ticket) {
    int t = threadIdx.x;
    int lane = t & 63, w = t >> 6;
    int i = blockIdx.x * 4 + w;
    int lab = labels[i];
    const float INF = __int_as_float(0x7f800000);

    if (blockIdx.x == 0 && t == 0) { *accum_ts = 0ull; *accum_vs = 0u; *ticket = 0u; }

    __shared__ unsigned int mbuck[4][NCLS];
    for (int c = lane; c < NCLS; c += 64) mbuck[w][c] = 0x7f800000u;
    asm volatile("s_waitcnt lgkmcnt(0)" ::: "memory");

    const float4* drow = (const float4*)(dist + (size_t)i * N);
    const int4*   lrow = (const int4*)labels;

    unsigned int t0v = 0xFFFFFFFFu, t1v = 0xFFFFFFFFu, t2v = 0xFFFFFFFFu, t3v = 0xFFFFFFFFu;
    int t0j = 0, t1j = 0, t2j = 0, t3j = 0;
    float bestu = -1.0f; int bestj = 0;
    int negc = 0;

    #pragma unroll
    for (int it = 0; it < 8; ++it) {
        int idx4 = it * 64 + lane;
        float4 dv = drow[idx4];
        int4   lv = lrow[idx4];
        #pragma unroll
        for (int e = 0; e < 4; ++e) {
            float dd = (e == 0) ? dv.x : (e == 1) ? dv.y : (e == 2) ? dv.z : dv.w;
            int   lj = (e == 0) ? lv.x : (e == 1) ? lv.y : (e == 2) ? lv.z : lv.w;
            int j = idx4 * 4 + e;
            unsigned int db = __float_as_uint(dd);
            bool self = (j == i);
            if (!self && db < mbuck[w][lj]) atomicMin(&mbuck[w][lj], db);
            if (lj == lab) {
                if (!self) {
                    float u = threefry_uniform((unsigned int)(i * N + j));
                    if (u > bestu || (u == bestu && j < bestj)) { bestu = u; bestj = j; }
                }
            } else {
                negc++;
                if (db < t3v) {
                    bool lt2 = db < t2v, lt1 = db < t1v, lt0 = db < t0v;
                    t3v = lt2 ? t2v : db;   t3j = lt2 ? t2j : j;
                    unsigned int n2v = lt1 ? t1v : db; int n2j = lt1 ? t1j : j;
                    t2v = lt2 ? n2v : t2v;  t2j = lt2 ? n2j : t2j;
                    unsigned int n1v = lt0 ? t0v : db; int n1j = lt0 ? t0j : j;
                    t1v = lt1 ? n1v : t1v;  t1j = lt1 ? n1j : t1j;
                    t0v = lt0 ? db : t0v;   t0j = lt0 ? j : t0j;
                }
            }
        }
    }

    #pragma unroll
    for (int o = 1; o < 64; o <<= 1) {
        float ou = __shfl_xor(bestu, o);
        int   oj = __shfl_xor(bestj, o);
        negc += __shfl_xor(negc, o);
        if (ou > bestu || (ou == bestu && oj < bestj)) { bestu = ou; bestj = oj; }
    }
    if (lane == 0) {
        bool has_pos = (bestu >= 0.0f);
        avalid[i] = (has_pos && negc >= 2) ? 1 : 0;
        d_ap[i]   = has_pos ? dist[(size_t)i * N + bestj] : 0.0f;
    }

    #pragma unroll 1
    for (int r = 0; r < K_NEG; ++r) {
        u64 myk = ((u64)t0v << 32) | (unsigned int)t0j;
        u64 kmin = myk;
        #pragma unroll
        for (int o = 1; o < 64; o <<= 1) {
            u64 ok = shfl_xor_u64(kmin, o);
            if (ok < kmin) kmin = ok;
        }
        unsigned int hv = (unsigned int)(kmin >> 32);
        bool fin = hv < 0x7f800000u;
        if (lane == 0) {
            d_an[i * K_NEG + r]  = fin ? __uint_as_float(hv) : INF;
            negs1[i * K_NEG + r] = fin ? (int)(kmin & 0xFFFFFFFFu) : 0;
        }
        bool won = fin && (myk == kmin);
        if (won) {
            t0v = t1v; t0j = t1j; t1v = t2v; t1j = t2j; t2v = t3v; t2j = t3j;
            t3v = 0xFFFFFFFFu; t3j = 0;
        }
        if (__any(won && t0v == 0xFFFFFFFFu)) {
            if (won && t0v == 0xFFFFFFFFu) {
                u64 best = 0xFFFFFFFFFFFFFFFFull;
                #pragma unroll 1
                for (int it = 0; it < 8; ++it) {
                    int idx4 = it * 64 + lane;
                    float4 dv = drow[idx4];
                    int4   lv = lrow[idx4];
                    #pragma unroll
                    for (int e = 0; e < 4; ++e) {
                        float dd = (e == 0) ? dv.x : (e == 1) ? dv.y : (e == 2) ? dv.z : dv.w;
                        int   lj = (e == 0) ? lv.x : (e == 1) ? lv.y : (e == 2) ? lv.z : lv.w;
                        int j = idx4 * 4 + e;
                        unsigned int db = __float_as_uint(dd);
                        if (lj != lab && db < 0x7f800000u) {
                            u64 kq = ((u64)db << 32) | (unsigned int)j;
                            if (kq > myk && kq < best) best = kq;
                        }
                    }
                }
                t0v = (unsigned int)(best >> 32);
                t0j = (int)(best & 0xFFFFFFFFu);
            }
        }
    }

    asm volatile("s_waitcnt lgkmcnt(0)" ::: "memory");
    {
        float m1v = __uint_as_float(mbuck[w][lane]);
        int   c1v = lane;
        float m2v = INF;
        #pragma unroll
        for (int p = 1; p < 4; ++p) {
            float b = __uint_as_float(mbuck[w][lane + p * 64]);
            if (b < m1v) { m2v = m1v; m1v = b; c1v = lane + p * 64; }
            else         { m2v = fminf(m2v, b); }
        }
        if (lane < NCLS - 256) {
            float b = __uint_as_float(mbuck[w][lane + 256]);
            if (b < m1v) { m2v = m1v; m1v = b; c1v = lane + 256; }
            else         { m2v = fminf(m2v, b); }
        }
        #pragma unroll
        for (int o = 1; o < 64; o <<= 1) {
            float o1 = __shfl_xor(m1v, o);
            int   oc = __shfl_xor(c1v, o);
            float o2 = __shfl_xor(m2v, o);
            if (o1 < m1v) { m2v = fminf(m1v, o2); m1v = o1; c1v = oc; }
            else          { m2v = fminf(m2v, o1); }
        }
        if (lane == 0) { rmin1[i] = m1v; rc1[i] = c1v; rmin2[i] = m2v; }
    }
}

// Kernel D: terms + finalize merged (fixed-point ticket reduction). (frozen)
__global__ void __launch_bounds__(256) reduce_kernel(
        const int* __restrict__ labels, const int* __restrict__ negs1,
        const float* __restrict__ d_an, const float* __restrict__ d_ap,
        const int* __restrict__ avalid, const float* __restrict__ rmin1,
        const int* __restrict__ rc1, const float* __restrict__ rmin2,
        const float* __restrict__ centerp,
        unsigned long long* __restrict__ accum_ts,
        unsigned int* __restrict__ accum_vs, unsigned int* __restrict__ ticket,
        float* __restrict__ out) {
    int t = threadIdx.x;
    int task = blockIdx.x * 256 + t;           // NRB*256 == N*K_NEG exactly
    const float INF = __int_as_float(0x7f800000);

    int i = task / K_NEG;
    int n1 = negs1[task];
    int lab = labels[i];
    float dn2 = (rc1[n1] == lab) ? rmin2[n1] : rmin1[n1];
    float dan = d_an[task];
    float dap = d_ap[i];
    float t1 = fmaxf(dap - dan + M1, 0.0f);
    float t2 = fmaxf(dap - dn2 + M2, 0.0f);
    bool valid = (avalid[i] != 0) && (dan < INF) && (dn2 < INF);
    float term = valid ? (t1 + t2) : 0.0f;

    __shared__ float a[256];
    __shared__ int   b[256];
    __shared__ int   lastFlag;
    a[t] = term; b[t] = valid ? 1 : 0;
    __syncthreads();
    for (int s = 128; s > 0; s >>= 1) {
        if (t < s) { a[t] += a[t + s]; b[t] += b[t + s]; }
        __syncthreads();
    }
    if (t == 0) {
        unsigned long long q = (unsigned long long)((double)a[0] * 1048576.0 + 0.5);
        atomicAdd(accum_ts, q);
        atomicAdd(accum_vs, (unsigned int)b[0]);
        __threadfence();
        unsigned int old = atomicAdd(ticket, 1u);
        lastFlag = (old == (unsigned int)(NRB - 1)) ? 1 : 0;
    }
    __syncthreads();
    if (lastFlag) {
        float cs = 0.f;
        for (int j = t; j < N; j += 256) cs += centerp[j];
        a[t] = cs;
        __syncthreads();
        for (int s = 128; s > 0; s >>= 1) {
            if (t < s) a[t] += a[t + s];
            __syncthreads();
        }
        if (t == 0) {
            unsigned long long ts_i = atomicAdd(accum_ts, 0ull);   // coherent read
            unsigned int       vs_i = atomicAdd(accum_vs, 0u);
            float tsum = (float)((double)ts_i / 1048576.0);
            float quad = (vs_i > 0u) ? (tsum / (float)vs_i) : 0.0f;
            out[0] = quad + CW * (a[0] / (float)N);
        }
    }
}

extern "C" void kernel_launch(void* const* d_in, const int* in_sizes, int n_in,
                              void* d_out, int out_size, void* d_ws, size_t ws_size,
                              hipStream_t stream) {
    const float* emb     = (const float*)d_in[0];
    const int*   labels  = (const int*)d_in[1];
    const float* centers = (const float*)d_in[2];
    float* out = (float*)d_out;

    char* ws = (char*)d_ws;
    unsigned short* xbf = (unsigned short*)ws;                 // 8 MB
    float* dist = (float*)(ws + (size_t)8 * 1024 * 1024);      // 16 MB
    char* p = ws + (size_t)24 * 1024 * 1024;
    float* sq      = (float*)p; p += N * 4;
    float* centerp = (float*)p; p += N * 4;
    float* d_ap    = (float*)p; p += N * 4;
    int*   avalid  = (int*)p;   p += N * 4;
    float* rmin1   = (float*)p; p += N * 4;
    int*   rc1     = (int*)p;   p += N * 4;
    float* rmin2   = (float*)p; p += N * 4;
    int*   negs1   = (int*)p;   p += N * K_NEG * 4;
    float* d_an    = (float*)p; p += N * K_NEG * 4;
    unsigned long long* accum_ts = (unsigned long long*)p; p += 8;
    unsigned int* accum_vs = (unsigned int*)p; p += 4;
    unsigned int* ticket   = (unsigned int*)p; p += 4;

    prep_kernel<<<N / 4, 256, 0, stream>>>(emb, labels, centers, xbf, sq, centerp);
    gemm_dist_kernel<<<NBLK, 256, 0, stream>>>(xbf, sq, dist);
    topk_kernel<<<N / 4, 256, 0, stream>>>(dist, labels, d_ap, avalid, negs1, d_an,
                                           rmin1, rc1, rmin2,
                                           accum_ts, accum_vs, ticket);
    reduce_kernel<<<NRB, 256, 0, stream>>>(labels, negs1, d_an, d_ap, avalid,
                                           rmin1, rc1, rmin2, centerp,
                                           accum_ts, accum_vs, ticket, out);
}

// Round 19
// 59.695 us; speedup vs baseline: 1.0468x; 1.0468x over previous
//
#include <hip/hip_runtime.h>
#include <hip/hip_bf16.h>

#define N 2048
#define FEAT 2048
#define K_NEG 10
#define NCLS 288
#define M1 0.3f
#define M2 0.3f
#define CW 0.01f

#define BT 64                 // square tile (symmetric/triangular grid)
#define GT (N / BT)           // 32 tiles per side
#define NBLK (GT * (GT + 1) / 2)   // 528 triangular blocks (528 % 8 == 0)
#define BK 64
#define NT (FEAT / BK)        // 32 K-steps
#define NRB (N * K_NEG / 256) // 80 reduce blocks

typedef __attribute__((ext_vector_type(8))) __bf16 bf16x8;
typedef __attribute__((ext_vector_type(4))) float f32x4;
typedef unsigned long long u64;

__device__ __forceinline__ unsigned short f32_to_bf16(float f) {
    unsigned int u = __float_as_uint(f);
    u += 0x7fffu + ((u >> 16) & 1u);   // round-to-nearest-even
    return (unsigned short)(u >> 16);
}

__device__ __forceinline__ unsigned int rotl32(unsigned int x, int d) {
    return (x << d) | (x >> (32 - d));
}

// Exact replica of jax.random.uniform(jax.random.key(42), (2048,2048)) at flat index f.
__device__ __attribute__((noinline)) float threefry_uniform(unsigned int f) {
    const unsigned int H = (unsigned int)(N) * (unsigned int)(N) / 2u;
    unsigned int x0, x1; int word;
    if (f < H) { x0 = f;     x1 = f + H; word = 0; }
    else       { x0 = f - H; x1 = f;     word = 1; }
    unsigned int ks[3];
    ks[0] = 0u; ks[1] = 42u; ks[2] = 0u ^ 42u ^ 0x1BD11BDAu;
    x0 += ks[0]; x1 += ks[1];
    const int rotA[4] = {13, 15, 26, 6};
    const int rotB[4] = {17, 29, 16, 24};
    #pragma unroll
    for (int i = 0; i < 5; ++i) {
        const int* r = (i & 1) ? rotB : rotA;
        #pragma unroll
        for (int j = 0; j < 4; ++j) {
            x0 += x1; x1 = rotl32(x1, r[j]); x1 ^= x0;
        }
        x0 += ks[(i + 1) % 3];
        x1 += ks[(i + 2) % 3] + (unsigned int)(i + 1);
    }
    unsigned int bits = (word == 0) ? x0 : x1;
    return __uint_as_float((bits >> 9) | 0x3f800000u) - 1.0f;
}

// async 16B global -> LDS (linear dest = wave-uniform base + lane*16)
__device__ __forceinline__ void gld16(const unsigned short* g, unsigned short* l) {
    __builtin_amdgcn_global_load_lds(
        (const __attribute__((address_space(1))) unsigned int*)g,
        (__attribute__((address_space(3))) unsigned int*)l,
        16, 0, 0);
}

__device__ __forceinline__ u64 shfl_xor_u64(u64 v, int mask) {
    unsigned int lo = (unsigned int)v, hi = (unsigned int)(v >> 32);
    lo = __shfl_xor(lo, mask);
    hi = __shfl_xor(hi, mask);
    return ((u64)hi << 32) | (u64)lo;
}

// Kernel A: prep, ONE WAVE PER ROW (512 blocks x 4 waves, no LDS, no barriers). (frozen)
__global__ void __launch_bounds__(256) prep_kernel(
        const float* __restrict__ emb, const int* __restrict__ labels,
        const float* __restrict__ centers, unsigned short* __restrict__ xbf,
        float* __restrict__ sq, float* __restrict__ centerp) {
    int t = threadIdx.x;
    int lane = t & 63, w = t >> 6;
    int i = blockIdx.x * 4 + w;
    int lab = labels[i];
    const float4* erow = (const float4*)(emb + (size_t)i * FEAT);
    const float4* crow = (const float4*)(centers + (size_t)lab * FEAT);
    uint2* xrow = (uint2*)(xbf + (size_t)i * FEAT);
    float ssum = 0.f, csum = 0.f;
    #pragma unroll
    for (int q = 0; q < 8; ++q) {
        int idx4 = q * 64 + lane;
        float4 e = erow[idx4];
        float4 c = crow[idx4];
        ssum += e.x*e.x + e.y*e.y + e.z*e.z + e.w*e.w;
        float dx = e.x-c.x, dy = e.y-c.y, dz = e.z-c.z, dw = e.w-c.w;
        csum += dx*dx + dy*dy + dz*dz + dw*dw;
        unsigned int w0 = (unsigned int)f32_to_bf16(e.x) | ((unsigned int)f32_to_bf16(e.y) << 16);
        unsigned int w1 = (unsigned int)f32_to_bf16(e.z) | ((unsigned int)f32_to_bf16(e.w) << 16);
        xrow[idx4] = make_uint2(w0, w1);
    }
    #pragma unroll
    for (int off = 32; off; off >>= 1) {
        ssum += __shfl_xor(ssum, off);
        csum += __shfl_xor(csum, off);
    }
    if (lane == 0) { sq[i] = ssum; centerp[i] = csum; }
}

// Kernel B: symmetric G = X X^T, triangular grid, depth-2 counted-vmcnt pipeline.
// (R17 config — measured best. XCD-chunked linear swizzle; super-tile remap
// regressed in R18 and was reverted.)
__global__ void __launch_bounds__(256) gemm_dist_kernel(
        const unsigned short* __restrict__ xbf, const float* __restrict__ sq,
        float* __restrict__ dist) {
    __shared__ __align__(16) unsigned short smem[6 * BT * BK];   // 48 KB: 3 x (As+Bs)
    unsigned short (*As)[BT * BK] = (unsigned short(*)[BT * BK])smem;
    unsigned short (*Bs)[BT * BK] = (unsigned short(*)[BT * BK])(smem + 3 * BT * BK);
    float (*Ts)[68] = (float(*)[68])smem;   // 17408 B, aliased post-K-loop

    // XCD-chunked swizzle (bijective: NBLK % 8 == 0), then triangular decode.
    int bid = blockIdx.x;
    int p = (bid & 7) * (NBLK / 8) + (bid >> 3);
    int by = 0, rem = p;
    while (rem >= GT - by) { rem -= GT - by; ++by; }
    int bx = by + rem;
    int brow0 = by * BT;
    int bcol0 = bx * BT;

    int t = threadIdx.x;
    int lane = t & 63, wid = t >> 6;
    int wr = wid >> 1, wc = wid & 1;          // 2 x 2 wave grid, 32x32 per wave
    f32x4 acc[2][2] = {};

    #define STAGE(buf, kelem) do {                                              \
        _Pragma("unroll")                                                       \
        for (int q = 0; q < 2; ++q) {                                           \
            int chunk = q * 256 + t;                                            \
            int row = chunk >> 3, c16 = chunk & 7;                              \
            int csrc = c16 ^ (row & 7);   /* involutive pre-swizzle */          \
            gld16(xbf + (size_t)(brow0 + row) * FEAT + (kelem) + csrc * 8,      \
                  &As[buf][chunk * 8]);                                         \
            gld16(xbf + (size_t)(bcol0 + row) * FEAT + (kelem) + csrc * 8,      \
                  &Bs[buf][chunk * 8]);                                         \
        } } while (0)

    STAGE(0, 0);
    STAGE(1, BK);

    for (int kt = 0; kt < NT; ++kt) {
        int cur = kt % 3;
        if (kt + 2 < NT) {
            STAGE((kt + 2) % 3, (kt + 2) * BK);                  // 12 in flight
            asm volatile("s_waitcnt vmcnt(8)" ::: "memory");     // tile-kt landed
        } else if (kt + 2 == NT) {
            asm volatile("s_waitcnt vmcnt(4)" ::: "memory");
        } else {
            asm volatile("s_waitcnt vmcnt(0)" ::: "memory");
        }
        __builtin_amdgcn_s_barrier();
        asm volatile("" ::: "memory");

        bf16x8 a[2][2], b[2][2];
        #pragma unroll
        for (int kk = 0; kk < 2; ++kk) {
            #pragma unroll
            for (int m = 0; m < 2; ++m) {
                int r = wr * 32 + m * 16 + (lane & 15);
                int slot = (kk * 4 + (lane >> 4)) ^ (r & 7);
                a[kk][m] = *(const bf16x8*)(&As[cur][r * BK + slot * 8]);
            }
            #pragma unroll
            for (int n = 0; n < 2; ++n) {
                int r = wc * 32 + n * 16 + (lane & 15);
                int slot = (kk * 4 + (lane >> 4)) ^ (r & 7);
                b[kk][n] = *(const bf16x8*)(&Bs[cur][r * BK + slot * 8]);
            }
        }
        #pragma unroll
        for (int m = 0; m < 2; ++m)
            #pragma unroll
            for (int n = 0; n < 2; ++n)
                #pragma unroll
                for (int kk = 0; kk < 2; ++kk)
                    acc[m][n] = __builtin_amdgcn_mfma_f32_16x16x32_bf16(a[kk][m], b[kk][n], acc[m][n], 0, 0, 0);

        asm volatile("" ::: "memory");
        __builtin_amdgcn_s_barrier();
        asm volatile("" ::: "memory");
    }
    #undef STAGE

    // Epilogue. C/D layout: col = lane&15, row = (lane>>4)*4 + reg  [m89/m91]
    bool offdiag = (bx != by);
    #pragma unroll
    for (int m = 0; m < 2; ++m) {
        int lrow_base = wr * 32 + m * 16 + (lane >> 4) * 4;
        #pragma unroll
        for (int n = 0; n < 2; ++n) {
            int lcol = wc * 32 + n * 16 + (lane & 15);
            int gcol = bcol0 + lcol;
            float sqc = sq[gcol];
            #pragma unroll
            for (int r = 0; r < 4; ++r) {
                int lrow = lrow_base + r;
                int grow = brow0 + lrow;
                float d2 = sq[grow] + sqc - 2.0f * acc[m][n][r];
                float d = sqrtf(fmaxf(d2, 1e-12f));
                dist[(size_t)grow * N + gcol] = d;
                if (offdiag) Ts[lcol][lrow] = d;
            }
        }
    }
    asm volatile("s_waitcnt lgkmcnt(0)" ::: "memory");
    __builtin_amdgcn_s_barrier();
    asm volatile("" ::: "memory");
    if (offdiag) {
        int tr = t >> 2, seg = t & 3;
        float4* dst = (float4*)(dist + (size_t)(bcol0 + tr) * N + brow0 + seg * 16);
        const float* srow = &Ts[tr][seg * 16];
        #pragma unroll
        for (int x = 0; x < 4; ++x)
            dst[x] = *(const float4*)(srow + x * 4);
    }
}

// Kernel C: ONE WAVE PER ROW topk (frozen) + zeroes the reduce accumulators.
__global__ void __launch_bounds__(256) topk_kernel(
        const float* __restrict__ dist, const int* __restrict__ labels,
        float* __restrict__ d_ap, int* __restrict__ avalid,
        int* __restrict__ negs1, float* __restrict__ d_an,
        float* __restrict__ rmin1, int* __restrict__ rc1, float* __restrict__ rmin2,
        unsigned long long* __restrict__ accum_ts,
        unsigned int* __restrict__ accum_vs, unsigned int* __restrict__ ticket) {
    int t = threadIdx.x;
    int lane = t & 63, w = t >> 6;
    int i = blockIdx.x * 4 + w;
    int lab = labels[i];
    const float INF = __int_as_float(0x7f800000);

    if (blockIdx.x == 0 && t == 0) { *accum_ts = 0ull; *accum_vs = 0u; *ticket = 0u; }

    __shared__ unsigned int mbuck[4][NCLS];
    for (int c = lane; c < NCLS; c += 64) mbuck[w][c] = 0x7f800000u;
    asm volatile("s_waitcnt lgkmcnt(0)" ::: "memory");

    const float4* drow = (const float4*)(dist + (size_t)i * N);
    const int4*   lrow = (const int4*)labels;

    unsigned int t0v = 0xFFFFFFFFu, t1v = 0xFFFFFFFFu, t2v = 0xFFFFFFFFu, t3v = 0xFFFFFFFFu;
    int t0j = 0, t1j = 0, t2j = 0, t3j = 0;
    float bestu = -1.0f; int bestj = 0;
    int negc = 0;

    #pragma unroll
    for (int it = 0; it < 8; ++it) {
        int idx4 = it * 64 + lane;
        float4 dv = drow[idx4];
        int4   lv = lrow[idx4];
        #pragma unroll
        for (int e = 0; e < 4; ++e) {
            float dd = (e == 0) ? dv.x : (e == 1) ? dv.y : (e == 2) ? dv.z : dv.w;
            int   lj = (e == 0) ? lv.x : (e == 1) ? lv.y : (e == 2) ? lv.z : lv.w;
            int j = idx4 * 4 + e;
            unsigned int db = __float_as_uint(dd);
            bool self = (j == i);
            if (!self && db < mbuck[w][lj]) atomicMin(&mbuck[w][lj], db);
            if (lj == lab) {
                if (!self) {
                    float u = threefry_uniform((unsigned int)(i * N + j));
                    if (u > bestu || (u == bestu && j < bestj)) { bestu = u; bestj = j; }
                }
            } else {
                negc++;
                if (db < t3v) {
                    bool lt2 = db < t2v, lt1 = db < t1v, lt0 = db < t0v;
                    t3v = lt2 ? t2v : db;   t3j = lt2 ? t2j : j;
                    unsigned int n2v = lt1 ? t1v : db; int n2j = lt1 ? t1j : j;
                    t2v = lt2 ? n2v : t2v;  t2j = lt2 ? n2j : t2j;
                    unsigned int n1v = lt0 ? t0v : db; int n1j = lt0 ? t0j : j;
                    t1v = lt1 ? n1v : t1v;  t1j = lt1 ? n1j : t1j;
                    t0v = lt0 ? db : t0v;   t0j = lt0 ? j : t0j;
                }
            }
        }
    }

    #pragma unroll
    for (int o = 1; o < 64; o <<= 1) {
        float ou = __shfl_xor(bestu, o);
        int   oj = __shfl_xor(bestj, o);
        negc += __shfl_xor(negc, o);
        if (ou > bestu || (ou == bestu && oj < bestj)) { bestu = ou; bestj = oj; }
    }
    if (lane == 0) {
        bool has_pos = (bestu >= 0.0f);
        avalid[i] = (has_pos && negc >= 2) ? 1 : 0;
        d_ap[i]   = has_pos ? dist[(size_t)i * N + bestj] : 0.0f;
    }

    #pragma unroll 1
    for (int r = 0; r < K_NEG; ++r) {
        u64 myk = ((u64)t0v << 32) | (unsigned int)t0j;
        u64 kmin = myk;
        #pragma unroll
        for (int o = 1; o < 64; o <<= 1) {
            u64 ok = shfl_xor_u64(kmin, o);
            if (ok < kmin) kmin = ok;
        }
        unsigned int hv = (unsigned int)(kmin >> 32);
        bool fin = hv < 0x7f800000u;
        if (lane == 0) {
            d_an[i * K_NEG + r]  = fin ? __uint_as_float(hv) : INF;
            negs1[i * K_NEG + r] = fin ? (int)(kmin & 0xFFFFFFFFu) : 0;
        }
        bool won = fin && (myk == kmin);
        if (won) {
            t0v = t1v; t0j = t1j; t1v = t2v; t1j = t2j; t2v = t3v; t2j = t3j;
            t3v = 0xFFFFFFFFu; t3j = 0;
        }
        if (__any(won && t0v == 0xFFFFFFFFu)) {
            if (won && t0v == 0xFFFFFFFFu) {
                u64 best = 0xFFFFFFFFFFFFFFFFull;
                #pragma unroll 1
                for (int it = 0; it < 8; ++it) {
                    int idx4 = it * 64 + lane;
                    float4 dv = drow[idx4];
                    int4   lv = lrow[idx4];
                    #pragma unroll
                    for (int e = 0; e < 4; ++e) {
                        float dd = (e == 0) ? dv.x : (e == 1) ? dv.y : (e == 2) ? dv.z : dv.w;
                        int   lj = (e == 0) ? lv.x : (e == 1) ? lv.y : (e == 2) ? lv.z : lv.w;
                        int j = idx4 * 4 + e;
                        unsigned int db = __float_as_uint(dd);
                        if (lj != lab && db < 0x7f800000u) {
                            u64 kq = ((u64)db << 32) | (unsigned int)j;
                            if (kq > myk && kq < best) best = kq;
                        }
                    }
                }
                t0v = (unsigned int)(best >> 32);
                t0j = (int)(best & 0xFFFFFFFFu);
            }
        }
    }

    asm volatile("s_waitcnt lgkmcnt(0)" ::: "memory");
    {
        float m1v = __uint_as_float(mbuck[w][lane]);
        int   c1v = lane;
        float m2v = INF;
        #pragma unroll
        for (int p = 1; p < 4; ++p) {
            float b = __uint_as_float(mbuck[w][lane + p * 64]);
            if (b < m1v) { m2v = m1v; m1v = b; c1v = lane + p * 64; }
            else         { m2v = fminf(m2v, b); }
        }
        if (lane < NCLS - 256) {
            float b = __uint_as_float(mbuck[w][lane + 256]);
            if (b < m1v) { m2v = m1v; m1v = b; c1v = lane + 256; }
            else         { m2v = fminf(m2v, b); }
        }
        #pragma unroll
        for (int o = 1; o < 64; o <<= 1) {
            float o1 = __shfl_xor(m1v, o);
            int   oc = __shfl_xor(c1v, o);
            float o2 = __shfl_xor(m2v, o);
            if (o1 < m1v) { m2v = fminf(m1v, o2); m1v = o1; c1v = oc; }
            else          { m2v = fminf(m2v, o1); }
        }
        if (lane == 0) { rmin1[i] = m1v; rc1[i] = c1v; rmin2[i] = m2v; }
    }
}

// Kernel D: terms + finalize merged (fixed-point ticket reduction). (frozen)
__global__ void __launch_bounds__(256) reduce_kernel(
        const int* __restrict__ labels, const int* __restrict__ negs1,
        const float* __restrict__ d_an, const float* __restrict__ d_ap,
        const int* __restrict__ avalid, const float* __restrict__ rmin1,
        const int* __restrict__ rc1, const float* __restrict__ rmin2,
        const float* __restrict__ centerp,
        unsigned long long* __restrict__ accum_ts,
        unsigned int* __restrict__ accum_vs, unsigned int* __restrict__ ticket,
        float* __restrict__ out) {
    int t = threadIdx.x;
    int task = blockIdx.x * 256 + t;           // NRB*256 == N*K_NEG exactly
    const float INF = __int_as_float(0x7f800000);

    int i = task / K_NEG;
    int n1 = negs1[task];
    int lab = labels[i];
    float dn2 = (rc1[n1] == lab) ? rmin2[n1] : rmin1[n1];
    float dan = d_an[task];
    float dap = d_ap[i];
    float t1 = fmaxf(dap - dan + M1, 0.0f);
    float t2 = fmaxf(dap - dn2 + M2, 0.0f);
    bool valid = (avalid[i] != 0) && (dan < INF) && (dn2 < INF);
    float term = valid ? (t1 + t2) : 0.0f;

    __shared__ float a[256];
    __shared__ int   b[256];
    __shared__ int   lastFlag;
    a[t] = term; b[t] = valid ? 1 : 0;
    __syncthreads();
    for (int s = 128; s > 0; s >>= 1) {
        if (t < s) { a[t] += a[t + s]; b[t] += b[t + s]; }
        __syncthreads();
    }
    if (t == 0) {
        unsigned long long q = (unsigned long long)((double)a[0] * 1048576.0 + 0.5);
        atomicAdd(accum_ts, q);
        atomicAdd(accum_vs, (unsigned int)b[0]);
        __threadfence();
        unsigned int old = atomicAdd(ticket, 1u);
        lastFlag = (old == (unsigned int)(NRB - 1)) ? 1 : 0;
    }
    __syncthreads();
    if (lastFlag) {
        float cs = 0.f;
        for (int j = t; j < N; j += 256) cs += centerp[j];
        a[t] = cs;
        __syncthreads();
        for (int s = 128; s > 0; s >>= 1) {
            if (t < s) a[t] += a[t + s];
            __syncthreads();
        }
        if (t == 0) {
            unsigned long long ts_i = atomicAdd(accum_ts, 0ull);   // coherent read
            unsigned int       vs_i = atomicAdd(accum_vs, 0u);
            float tsum = (float)((double)ts_i / 1048576.0);
            float quad = (vs_i > 0u) ? (tsum / (float)vs_i) : 0.0f;
            out[0] = quad + CW * (a[0] / (float)N);
        }
    }
}

extern "C" void kernel_launch(void* const* d_in, const int* in_sizes, int n_in,
                              void* d_out, int out_size, void* d_ws, size_t ws_size,
                              hipStream_t stream) {
    const float* emb     = (const float*)d_in[0];
    const int*   labels  = (const int*)d_in[1];
    const float* centers = (const float*)d_in[2];
    float* out = (float*)d_out;

    char* ws = (char*)d_ws;
    unsigned short* xbf = (unsigned short*)ws;                 // 8 MB
    float* dist = (float*)(ws + (size_t)8 * 1024 * 1024);      // 16 MB
    char* p = ws + (size_t)24 * 1024 * 1024;
    float* sq      = (float*)p; p += N * 4;
    float* centerp = (float*)p; p += N * 4;
    float* d_ap    = (float*)p; p += N * 4;
    int*   avalid  = (int*)p;   p += N * 4;
    float* rmin1   = (float*)p; p += N * 4;
    int*   rc1     = (int*)p;   p += N * 4;
    float* rmin2   = (float*)p; p += N * 4;
    int*   negs1   = (int*)p;   p += N * K_NEG * 4;
    float* d_an    = (float*)p; p += N * K_NEG * 4;
    unsigned long long* accum_ts = (unsigned long long*)p; p += 8;
    unsigned int* accum_vs = (unsigned int*)p; p += 4;
    unsigned int* ticket   = (unsigned int*)p; p += 4;

    prep_kernel<<<N / 4, 256, 0, stream>>>(emb, labels, centers, xbf, sq, centerp);
    gemm_dist_kernel<<<NBLK, 256, 0, stream>>>(xbf, sq, dist);
    topk_kernel<<<N / 4, 256, 0, stream>>>(dist, labels, d_ap, avalid, negs1, d_an,
                                           rmin1, rc1, rmin2,
                                           accum_ts, accum_vs, ticket);
    reduce_kernel<<<NRB, 256, 0, stream>>>(labels, negs1, d_an, d_ap, avalid,
                                           rmin1, rc1, rmin2, centerp,
                                           accum_ts, accum_vs, ticket, out);
}